// Round 2
// baseline (176.287 us; speedup 1.0000x reference)
//
#include <hip/hip_runtime.h>
#include <stdint.h>

#define BB 8
#define SS 8192
#define DD 512

#define TOK_CS 256
#define TOK_CE 257
#define TOK_MEM 258
#define TOK_TS 259
#define TOK_TE 260

typedef float vfloat4 __attribute__((ext_vector_type(4)));

// ---------------------------------------------------------------------------
// Kernel 1: per-row metadata. One block per batch row.
// meta[pos] layout: bits 0..47  = 48-bit addr one-hot mask
//                   bit  48     = MARK_TS   (d=456)
//                   bit  49     = MARK_TE   (d=457)
//                   bit  50     = MEM_EXEC  (d=458)
//                   bits 52..60 = token id (9 bits)
// ---------------------------------------------------------------------------
__global__ __launch_bounds__(256) void meta_kernel(const int* __restrict__ tokens,
                                                   unsigned long long* __restrict__ meta) {
    __shared__ int t[SS];          // 32 KB
    __shared__ int chunkmax[256];
    __shared__ int cemin_sh[256];

    const int b = blockIdx.x;
    const int tid = threadIdx.x;
    const int* rt = tokens + (size_t)b * SS;

    // load tokens into LDS (coalesced) + track min CODE_END index
    int cemin = SS;
    for (int i = tid; i < SS; i += 256) {
        int v = rt[i];
        t[i] = v;
        if (v == TOK_CE && i < cemin) cemin = i;
    }
    cemin_sh[tid] = cemin;
    __syncthreads();
    for (int off = 128; off > 0; off >>= 1) {
        if (tid < off) {
            int o = cemin_sh[tid + off];
            if (o < cemin_sh[tid]) cemin_sh[tid] = o;
        }
        __syncthreads();
    }
    const int first_ce = cemin_sh[0];

    // chunk-local max of (is_cs ? idx : -1); chunk = 32 contiguous positions
    const int c0 = tid * 32;
    int cm = -1;
    for (int i = c0; i < c0 + 32; ++i)
        if (t[i] == TOK_CS) cm = i;   // indices ascend, so last hit is the max
    chunkmax[tid] = cm;
    __syncthreads();

    // exclusive prefix max over chunks (O(tid) LDS reads; trivial cost)
    int carry = -1;
    for (int c = 0; c < tid; ++c) {
        int v = chunkmax[c];
        if (v > carry) carry = v;
    }

    unsigned long long* mrow = meta + (size_t)b * SS;
    int cs = carry;
    for (int i = c0; i < c0 + 32; ++i) {
        const int v = t[i];
        if (v == TOK_CS) cs = i;

        unsigned long long m = ((unsigned long long)v) << 52;

        // ---- code-region address one-hot ----
        if (cs >= 0 && i < first_ce && v < 256) {
            int sp = i - cs - 1;
            if (sp >= 0) {
                int bo = sp & 7;
                if (bo < 5) {
                    int addr = ((sp >> 3) << 3) + 2 + bo;  // PC_OFFSET=2
                    addr &= 4095;
                    m |= (1ull << (addr & 15))
                       | (1ull << (16 + ((addr >> 4) & 15)))
                       | (1ull << (32 + ((addr >> 8) & 15)));
                }
            }
        }

        // ---- MEM-op scatter, gathered: positions j = i-5-off with tok[j]==MEM ----
        #pragma unroll
        for (int off = 0; off < 4; ++off) {
            int jj = i - 5 - off;
            if (jj >= 0 && (jj + 8) < SS && t[jj] == TOK_MEM) {
                int a = ((t[jj + 1] | (t[jj + 2] << 8)) & 4095) + off;
                a &= 4095;
                m |= (1ull << (a & 15))
                   | (1ull << (16 + ((a >> 4) & 15)))
                   | (1ull << (32 + ((a >> 8) & 15)));
            }
        }

        // ---- flag dims ----
        if (v == TOK_TS) m |= (1ull << 48);
        if (v == TOK_TE) m |= (1ull << 49);
        if (v == TOK_MEM && (i + 8) < SS) m |= (1ull << 50);

        mrow[i] = m;
    }
}

// ---------------------------------------------------------------------------
// Kernel 2: writer. 128 lanes per position, one float4 per lane.
// ---------------------------------------------------------------------------
__global__ __launch_bounds__(256) void write_kernel(const vfloat4* __restrict__ embed4,
                                                    const unsigned long long* __restrict__ meta,
                                                    vfloat4* __restrict__ out) {
    const int gid = blockIdx.x * 256 + threadIdx.x;
    const int pos = gid >> 7;     // position index in [0, B*S)
    const int k = gid & 127;      // float4 index within the 512-dim row

    const unsigned long long m = meta[pos];
    const int tok = (int)(m >> 52);

    vfloat4 v = embed4[tok * 128 + k];

    if (k >= 51 && k <= 63) {
        // dims [204..255]; override range is [206..253] via mask bits r=d-206
        const int d0 = k * 4;
        #pragma unroll
        for (int j = 0; j < 4; ++j) {
            int r = d0 + j - 206;
            if (r >= 0 && r < 48 && ((m >> r) & 1ull)) v[j] = 1.0f;
        }
    } else if (k == 114) {
        // dims 456,457,458 -> bits 48,49,50
        #pragma unroll
        for (int j = 0; j < 3; ++j) {
            if ((m >> (48 + j)) & 1ull) v[j] = 1.0f;
        }
    }

    __builtin_nontemporal_store(v, &out[(size_t)pos * 128 + k]);
}

extern "C" void kernel_launch(void* const* d_in, const int* in_sizes, int n_in,
                              void* d_out, int out_size, void* d_ws, size_t ws_size,
                              hipStream_t stream) {
    const float* embed = (const float*)d_in[0];       // [272, 512] fp32
    const int* tokens = (const int*)d_in[1];          // [8, 8192] int32
    unsigned long long* meta = (unsigned long long*)d_ws;  // 8*8192*8 = 512 KB

    meta_kernel<<<BB, 256, 0, stream>>>(tokens, meta);

    const int total_f4 = BB * SS * (DD / 4);          // 8,388,608
    write_kernel<<<total_f4 / 256, 256, 0, stream>>>(
        (const vfloat4*)embed, meta, (vfloat4*)d_out);
}

// Round 3
// 172.084 us; speedup vs baseline: 1.0244x; 1.0244x over previous
//
#include <hip/hip_runtime.h>
#include <stdint.h>

#define BB 8
#define SS 8192
#define DD 512

#define TOK_CS 256
#define TOK_CE 257
#define TOK_MEM 258
#define TOK_TS 259
#define TOK_TE 260

typedef float vfloat4 __attribute__((ext_vector_type(4)));

// padded LDS index: one pad int per 32 -> lane tid's chunk base lands on
// bank (tid) instead of all chunks sharing bank 0. Kills the 64-lane
// same-bank serialization of the chunk-per-thread layout.
__device__ __forceinline__ int ti(int i) { return i + (i >> 5); }

// ---------------------------------------------------------------------------
// Kernel 1: per-row metadata. One block per batch row.
// meta[pos] layout: bits 0..47  = 48-bit addr one-hot mask
//                   bit  48     = MARK_TS   (d=456)
//                   bit  49     = MARK_TE   (d=457)
//                   bit  50     = MEM_EXEC  (d=458)
//                   bits 52..60 = token id (9 bits)
// ---------------------------------------------------------------------------
__global__ __launch_bounds__(256) void meta_kernel(const int* __restrict__ tokens,
                                                   unsigned long long* __restrict__ meta) {
    __shared__ int t[SS + SS / 32];   // padded: 33 KB
    __shared__ int chunkmax[256];
    __shared__ int cemin_sh[256];

    const int b = blockIdx.x;
    const int tid = threadIdx.x;
    const int* rt = tokens + (size_t)b * SS;

    // load tokens into LDS (coalesced) + track min CODE_END index
    int cemin = SS;
    for (int i = tid; i < SS; i += 256) {
        int v = rt[i];
        t[ti(i)] = v;
        if (v == TOK_CE && i < cemin) cemin = i;
    }
    cemin_sh[tid] = cemin;
    __syncthreads();
    for (int off = 128; off > 0; off >>= 1) {
        if (tid < off) {
            int o = cemin_sh[tid + off];
            if (o < cemin_sh[tid]) cemin_sh[tid] = o;
        }
        __syncthreads();
    }
    const int first_ce = cemin_sh[0];

    // chunk-local max of (is_cs ? idx : -1); chunk = 32 contiguous positions
    const int c0 = tid * 32;
    int cm = -1;
    for (int i = c0; i < c0 + 32; ++i)
        if (t[ti(i)] == TOK_CS) cm = i;   // indices ascend: last hit = max
    chunkmax[tid] = cm;
    __syncthreads();

    // exclusive prefix max over chunks (wave-uniform broadcast reads; cheap)
    int carry = -1;
    for (int c = 0; c < tid; ++c) {
        int v = chunkmax[c];
        if (v > carry) carry = v;
    }

    unsigned long long* mrow = meta + (size_t)b * SS;
    int cs = carry;
    for (int i = c0; i < c0 + 32; ++i) {
        const int v = t[ti(i)];
        if (v == TOK_CS) cs = i;

        unsigned long long m = ((unsigned long long)v) << 52;

        // ---- code-region address one-hot ----
        if (cs >= 0 && i < first_ce && v < 256) {
            int sp = i - cs - 1;
            if (sp >= 0) {
                int bo = sp & 7;
                if (bo < 5) {
                    int addr = ((sp >> 3) << 3) + 2 + bo;  // PC_OFFSET=2
                    addr &= 4095;
                    m |= (1ull << (addr & 15))
                       | (1ull << (16 + ((addr >> 4) & 15)))
                       | (1ull << (32 + ((addr >> 8) & 15)));
                }
            }
        }

        // ---- MEM-op scatter, gathered: j = i-5-off with tok[j]==MEM ----
        #pragma unroll
        for (int off = 0; off < 4; ++off) {
            int jj = i - 5 - off;
            if (jj >= 0 && (jj + 8) < SS && t[ti(jj)] == TOK_MEM) {
                int a = ((t[ti(jj + 1)] | (t[ti(jj + 2)] << 8)) & 4095) + off;
                a &= 4095;
                m |= (1ull << (a & 15))
                   | (1ull << (16 + ((a >> 4) & 15)))
                   | (1ull << (32 + ((a >> 8) & 15)));
            }
        }

        // ---- flag dims ----
        if (v == TOK_TS) m |= (1ull << 48);
        if (v == TOK_TE) m |= (1ull << 49);
        if (v == TOK_MEM && (i + 8) < SS) m |= (1ull << 50);

        mrow[i] = m;
    }
}

// ---------------------------------------------------------------------------
// Kernel 2: writer. 128 lanes per position, one float4 per lane.
// ---------------------------------------------------------------------------
__global__ __launch_bounds__(256) void write_kernel(const vfloat4* __restrict__ embed4,
                                                    const unsigned long long* __restrict__ meta,
                                                    vfloat4* __restrict__ out) {
    const int gid = blockIdx.x * 256 + threadIdx.x;
    const int pos = gid >> 7;     // position index in [0, B*S)
    const int k = gid & 127;      // float4 index within the 512-dim row

    const unsigned long long m = meta[pos];
    const int tok = (int)(m >> 52);

    vfloat4 v = embed4[tok * 128 + k];

    if (k >= 51 && k <= 63) {
        // dims [204..255]; override range is [206..253] via mask bits r=d-206
        const int d0 = k * 4;
        #pragma unroll
        for (int j = 0; j < 4; ++j) {
            int r = d0 + j - 206;
            if (r >= 0 && r < 48 && ((m >> r) & 1ull)) v[j] = 1.0f;
        }
    } else if (k == 114) {
        // dims 456,457,458 -> bits 48,49,50
        #pragma unroll
        for (int j = 0; j < 3; ++j) {
            if ((m >> (48 + j)) & 1ull) v[j] = 1.0f;
        }
    }

    __builtin_nontemporal_store(v, &out[(size_t)pos * 128 + k]);
}

extern "C" void kernel_launch(void* const* d_in, const int* in_sizes, int n_in,
                              void* d_out, int out_size, void* d_ws, size_t ws_size,
                              hipStream_t stream) {
    const float* embed = (const float*)d_in[0];       // [272, 512] fp32
    const int* tokens = (const int*)d_in[1];          // [8, 8192] int32
    unsigned long long* meta = (unsigned long long*)d_ws;  // 8*8192*8 = 512 KB

    meta_kernel<<<BB, 256, 0, stream>>>(tokens, meta);

    const int total_f4 = BB * SS * (DD / 4);          // 8,388,608
    write_kernel<<<total_f4 / 256, 256, 0, stream>>>(
        (const vfloat4*)embed, meta, (vfloat4*)d_out);
}

// Round 4
// 154.461 us; speedup vs baseline: 1.1413x; 1.1141x over previous
//
#include <hip/hip_runtime.h>
#include <stdint.h>

#define BB 8
#define SS 8192
#define DD 512

#define TOK_CS 256
#define TOK_CE 257
#define TOK_MEM 258
#define TOK_TS 259
#define TOK_TE 260

#define SEGS 64            // blocks per row
#define PB 128             // positions per block (SS / SEGS)

typedef float vfloat4 __attribute__((ext_vector_type(4)));

// ---------------------------------------------------------------------------
// Single fused kernel. Grid = B * SEGS = 512 blocks, 256 threads.
// Each block owns 128 consecutive positions of one row:
//   phase A: redundant prefix scan of tokens[0..start) -> carry (maxCS, anyCE)
//   phase B: shfl inclusive scan over the 128 local positions -> meta word
//   phase C: streamed coalesced writer (128 f4 lanes x 2 positions / iter)
// meta bits: 0..47 one-hot mask | 48 TS | 49 TE | 50 MEM_EXEC | 52.. token
// ---------------------------------------------------------------------------
__global__ __launch_bounds__(256) void fused_kernel(const int* __restrict__ tokens,
                                                    const vfloat4* __restrict__ embed4,
                                                    vfloat4* __restrict__ out) {
    __shared__ int tloc[PB + 8];              // local tokens with 8-token front halo
    __shared__ unsigned long long mlds[PB];   // per-position meta
    __shared__ int rcs[256];
    __shared__ int rce[256];
    __shared__ int wtot_cs, wtot_ce;

    const int blk = blockIdx.x;
    const int row = blk >> 6;                 // / SEGS
    const int seg = blk & 63;
    const int start = seg * PB;
    const int tid = threadIdx.x;
    const int* rt = tokens + (size_t)row * SS;

    // ---- phase A: prefix carry over [0, start) ----
    int maxcs = -1, anyce = 0;
    for (int j = tid; j < start; j += 256) {   // strided; later j larger -> last hit = max
        int v = rt[j];
        if (v == TOK_CS) maxcs = j;
        if (v == TOK_CE) anyce = 1;
    }
    rcs[tid] = maxcs;
    rce[tid] = anyce;

    // local tokens + halo while the reduction arrays settle
    for (int h = tid; h < PB + 8; h += 256) {
        int g = start - 8 + h;
        tloc[h] = (g >= 0) ? rt[g] : 0;       // 0 is never MEM
    }
    __syncthreads();
    for (int off = 128; off > 0; off >>= 1) {
        if (tid < off) {
            int a = rcs[tid + off];
            if (a > rcs[tid]) rcs[tid] = a;
            rce[tid] |= rce[tid + off];
        }
        __syncthreads();
    }
    const int carry_cs = rcs[0];
    const int carry_ce = rce[0];

    // ---- phase B: inclusive (max,or) scan over 128 local positions ----
    int myv = 0, cs_scan = -1, ce_scan = 0;
    if (tid < PB) {
        myv = tloc[8 + tid];
        cs_scan = (myv == TOK_CS) ? (start + tid) : -1;
        ce_scan = (myv == TOK_CE) ? 1 : 0;
    }
    const int lane = tid & 63;
    #pragma unroll
    for (int off = 1; off < 64; off <<= 1) {
        int u = __shfl_up(cs_scan, off);
        int w = __shfl_up(ce_scan, off);
        if (lane >= off) {
            if (u > cs_scan) cs_scan = u;
            ce_scan |= w;
        }
    }
    if (tid == 63) { wtot_cs = cs_scan; wtot_ce = ce_scan; }
    __syncthreads();
    if (tid >= 64 && tid < PB) {
        if (wtot_cs > cs_scan) cs_scan = wtot_cs;
        ce_scan |= wtot_ce;
    }

    if (tid < PB) {
        if (carry_cs > cs_scan) cs_scan = carry_cs;
        ce_scan |= carry_ce;

        const int i = start + tid;
        const int v = myv;
        unsigned long long m = ((unsigned long long)v) << 52;

        // code-region address one-hot
        if (cs_scan >= 0 && ce_scan == 0 && v < 256) {
            int sp = i - cs_scan - 1;
            if (sp >= 0) {
                int bo = sp & 7;
                if (bo < 5) {
                    int addr = ((sp >> 3) << 3) + 2 + bo;   // PC_OFFSET=2
                    addr &= 4095;
                    m |= (1ull << (addr & 15))
                       | (1ull << (16 + ((addr >> 4) & 15)))
                       | (1ull << (32 + ((addr >> 8) & 15)));
                }
            }
        }

        // MEM-op scatter, gathered from up to 8 positions back
        #pragma unroll
        for (int off = 0; off < 4; ++off) {
            int jj = i - 5 - off;
            int lj = jj - start + 8;            // >= 0 since jj >= i-8 >= start-8
            if (jj >= 0 && (jj + 8) < SS && tloc[lj] == TOK_MEM) {
                int a = ((tloc[lj + 1] | (tloc[lj + 2] << 8)) & 4095) + off;
                a &= 4095;
                m |= (1ull << (a & 15))
                   | (1ull << (16 + ((a >> 4) & 15)))
                   | (1ull << (32 + ((a >> 8) & 15)));
            }
        }

        // flag dims
        if (v == TOK_TS) m |= (1ull << 48);
        if (v == TOK_TE) m |= (1ull << 49);
        if (v == TOK_MEM && (i + 8) < SS) m |= (1ull << 50);

        mlds[tid] = m;
    }
    __syncthreads();

    // ---- phase C: writer. 2 positions / iter, 128 f4 lanes each ----
    const int k = tid & 127;
    const int half = tid >> 7;                  // 0 or 1
    vfloat4* orow = out + ((size_t)row * SS + start) * 128;

    #pragma unroll 4
    for (int it = 0; it < PB / 2; ++it) {
        const int pl = it * 2 + half;
        const unsigned long long m = mlds[pl];
        const int tok = (int)(m >> 52);

        vfloat4 v = embed4[tok * 128 + k];

        if (k >= 51 && k <= 63) {
            const int d0 = k * 4;
            #pragma unroll
            for (int j = 0; j < 4; ++j) {
                int r = d0 + j - 206;
                if (r >= 0 && r < 48 && ((m >> r) & 1ull)) v[j] = 1.0f;
            }
        } else if (k == 114) {
            #pragma unroll
            for (int j = 0; j < 3; ++j) {
                if ((m >> (48 + j)) & 1ull) v[j] = 1.0f;
            }
        }

        __builtin_nontemporal_store(v, &orow[pl * 128 + k]);
    }
}

extern "C" void kernel_launch(void* const* d_in, const int* in_sizes, int n_in,
                              void* d_out, int out_size, void* d_ws, size_t ws_size,
                              hipStream_t stream) {
    const float* embed = (const float*)d_in[0];   // [272, 512] fp32
    const int* tokens = (const int*)d_in[1];      // [8, 8192] int32

    fused_kernel<<<BB * SEGS, 256, 0, stream>>>(
        tokens, (const vfloat4*)embed, (vfloat4*)d_out);
}

// Round 5
// 150.682 us; speedup vs baseline: 1.1699x; 1.0251x over previous
//
#include <hip/hip_runtime.h>
#include <stdint.h>

#define BB 8
#define SS 8192
#define DD 512

#define TOK_CS 256
#define TOK_CE 257
#define TOK_MEM 258
#define TOK_TS 259
#define TOK_TE 260

#define SEGS 128           // blocks per row
#define PB 64              // positions per block (SS / SEGS)

typedef float vfloat4 __attribute__((ext_vector_type(4)));

// ---------------------------------------------------------------------------
// Single fused kernel. Grid = B * SEGS = 1024 blocks, 256 threads
// (4 blocks/CU, 16 waves/CU -> enough TLP to hide the L2 embed-gather
// latency in the writer phase).
// Each block owns PB=64 consecutive positions of one row:
//   phase A: redundant prefix scan of tokens[0..start) -> carry (maxCS, anyCE)
//   phase B: single-wave shfl inclusive scan over the 64 local positions
//   phase C: streamed coalesced writer (128 f4 lanes x 2 positions / iter,
//            unroll 8 -> 8 independent gather->store chains in flight)
// meta bits: 0..47 one-hot mask | 48 TS | 49 TE | 50 MEM_EXEC | 52.. token
// ---------------------------------------------------------------------------
__global__ __launch_bounds__(256) void fused_kernel(const int* __restrict__ tokens,
                                                    const vfloat4* __restrict__ embed4,
                                                    vfloat4* __restrict__ out) {
    __shared__ int tloc[PB + 8];              // local tokens with 8-token front halo
    __shared__ unsigned long long mlds[PB];   // per-position meta
    __shared__ int rcs[256];
    __shared__ int rce[256];

    const int blk = blockIdx.x;
    const int row = blk >> 7;                 // / SEGS
    const int seg = blk & (SEGS - 1);
    const int start = seg * PB;
    const int tid = threadIdx.x;
    const int* rt = tokens + (size_t)row * SS;

    // ---- phase A: prefix carry over [0, start) ----
    int maxcs = -1, anyce = 0;
    for (int j = tid; j < start; j += 256) {   // strided; later j larger -> last hit = max
        int v = rt[j];
        if (v == TOK_CS) maxcs = j;
        if (v == TOK_CE) anyce = 1;
    }
    rcs[tid] = maxcs;
    rce[tid] = anyce;

    // local tokens + halo while the reduction arrays settle
    if (tid < PB + 8) {
        int g = start - 8 + tid;
        tloc[tid] = (g >= 0) ? rt[g] : 0;     // 0 is never MEM
    }
    __syncthreads();
    for (int off = 128; off > 0; off >>= 1) {
        if (tid < off) {
            int a = rcs[tid + off];
            if (a > rcs[tid]) rcs[tid] = a;
            rce[tid] |= rce[tid + off];
        }
        __syncthreads();
    }
    const int carry_cs = rcs[0];
    const int carry_ce = rce[0];

    // ---- phase B: single-wave inclusive (max,or) scan over 64 positions ----
    if (tid < PB) {
        const int myv = tloc[8 + tid];
        int cs_scan = (myv == TOK_CS) ? (start + tid) : -1;
        int ce_scan = (myv == TOK_CE) ? 1 : 0;

        #pragma unroll
        for (int off = 1; off < 64; off <<= 1) {
            int u = __shfl_up(cs_scan, off);
            int w = __shfl_up(ce_scan, off);
            if (tid >= off) {
                if (u > cs_scan) cs_scan = u;
                ce_scan |= w;
            }
        }
        if (carry_cs > cs_scan) cs_scan = carry_cs;
        ce_scan |= carry_ce;

        const int i = start + tid;
        const int v = myv;
        unsigned long long m = ((unsigned long long)v) << 52;

        // code-region address one-hot
        if (cs_scan >= 0 && ce_scan == 0 && v < 256) {
            int sp = i - cs_scan - 1;
            if (sp >= 0) {
                int bo = sp & 7;
                if (bo < 5) {
                    int addr = ((sp >> 3) << 3) + 2 + bo;   // PC_OFFSET=2
                    addr &= 4095;
                    m |= (1ull << (addr & 15))
                       | (1ull << (16 + ((addr >> 4) & 15)))
                       | (1ull << (32 + ((addr >> 8) & 15)));
                }
            }
        }

        // MEM-op scatter, gathered from up to 8 positions back
        #pragma unroll
        for (int off = 0; off < 4; ++off) {
            int jj = i - 5 - off;
            int lj = jj - start + 8;            // >= 0 since jj >= i-8 >= start-8
            if (jj >= 0 && (jj + 8) < SS && tloc[lj] == TOK_MEM) {
                int a = ((tloc[lj + 1] | (tloc[lj + 2] << 8)) & 4095) + off;
                a &= 4095;
                m |= (1ull << (a & 15))
                   | (1ull << (16 + ((a >> 4) & 15)))
                   | (1ull << (32 + ((a >> 8) & 15)));
            }
        }

        // flag dims
        if (v == TOK_TS) m |= (1ull << 48);
        if (v == TOK_TE) m |= (1ull << 49);
        if (v == TOK_MEM && (i + 8) < SS) m |= (1ull << 50);

        mlds[tid] = m;
    }
    __syncthreads();

    // ---- phase C: writer. 2 positions / iter, 128 f4 lanes each ----
    const int k = tid & 127;
    const int half = tid >> 7;                  // 0 or 1
    vfloat4* orow = out + ((size_t)row * SS + start) * 128;

    #pragma unroll 8
    for (int it = 0; it < PB / 2; ++it) {
        const int pl = it * 2 + half;
        const unsigned long long m = mlds[pl];
        const int tok = (int)(m >> 52);

        vfloat4 v = embed4[tok * 128 + k];

        if (k >= 51 && k <= 63) {
            const int d0 = k * 4;
            #pragma unroll
            for (int j = 0; j < 4; ++j) {
                int r = d0 + j - 206;
                if (r >= 0 && r < 48 && ((m >> r) & 1ull)) v[j] = 1.0f;
            }
        } else if (k == 114) {
            #pragma unroll
            for (int j = 0; j < 3; ++j) {
                if ((m >> (48 + j)) & 1ull) v[j] = 1.0f;
            }
        }

        __builtin_nontemporal_store(v, &orow[pl * 128 + k]);
    }
}

extern "C" void kernel_launch(void* const* d_in, const int* in_sizes, int n_in,
                              void* d_out, int out_size, void* d_ws, size_t ws_size,
                              hipStream_t stream) {
    const float* embed = (const float*)d_in[0];   // [272, 512] fp32
    const int* tokens = (const int*)d_in[1];      // [8, 8192] int32

    fused_kernel<<<BB * SEGS, 256, 0, stream>>>(
        tokens, (const vfloat4*)embed, (vfloat4*)d_out);
}

// Round 6
// 149.965 us; speedup vs baseline: 1.1755x; 1.0048x over previous
//
#include <hip/hip_runtime.h>
#include <stdint.h>

#define BB 8
#define SS 8192
#define DD 512

#define TOK_CS 256
#define TOK_CE 257
#define TOK_MEM 258
#define TOK_TS 259
#define TOK_TE 260

#define SEGS 256           // blocks per row
#define PB 32              // positions per block (SS / SEGS)

typedef float vfloat4 __attribute__((ext_vector_type(4)));

// ---------------------------------------------------------------------------
// Single fused kernel. Grid = B * SEGS = 2048 blocks, 256 threads
// (8 blocks/CU = 32 waves/CU, the max -> as much TLP as the CU can hold to
// saturate the HBM write stream).
// Each block owns PB=32 consecutive positions of one row:
//   phase A: redundant prefix scan of tokens[0..start) -> carry (maxCS, anyCE)
//   phase B: 32-lane shfl inclusive scan over the local positions
//   phase C: streamed coalesced writer (128 f4 lanes x 2 positions / iter)
// meta bits: 0..47 one-hot mask | 48 TS | 49 TE | 50 MEM_EXEC | 52.. token
// ---------------------------------------------------------------------------
__global__ __launch_bounds__(256) void fused_kernel(const int* __restrict__ tokens,
                                                    const vfloat4* __restrict__ embed4,
                                                    vfloat4* __restrict__ out) {
    __shared__ int tloc[PB + 8];              // local tokens with 8-token front halo
    __shared__ unsigned long long mlds[PB];   // per-position meta
    __shared__ int rcs[4];
    __shared__ int rce[4];

    const int blk = blockIdx.x;
    const int row = blk >> 8;                 // / SEGS
    const int seg = blk & (SEGS - 1);
    const int start = seg * PB;
    const int tid = threadIdx.x;
    const int lane = tid & 63;
    const int wv = tid >> 6;
    const int* rt = tokens + (size_t)row * SS;

    // ---- phase A: prefix carry over [0, start) ----
    int maxcs = -1, anyce = 0;
    for (int j = tid; j < start; j += 256) {   // strided; later j larger -> last hit = max
        int v = rt[j];
        if (v == TOK_CS) maxcs = j;
        if (v == TOK_CE) anyce = 1;
    }
    // wave-level reduce (max, or)
    #pragma unroll
    for (int off = 32; off > 0; off >>= 1) {
        int a = __shfl_down(maxcs, off);
        int b = __shfl_down(anyce, off);
        if (a > maxcs) maxcs = a;
        anyce |= b;
    }
    if (lane == 0) { rcs[wv] = maxcs; rce[wv] = anyce; }

    // local tokens + halo
    if (tid < PB + 8) {
        int g = start - 8 + tid;
        tloc[tid] = (g >= 0) ? rt[g] : 0;     // 0 is never MEM
    }
    __syncthreads();
    int carry_cs = rcs[0], carry_ce = rce[0];
    #pragma unroll
    for (int w = 1; w < 4; ++w) {
        if (rcs[w] > carry_cs) carry_cs = rcs[w];
        carry_ce |= rce[w];
    }

    // ---- phase B: 32-lane inclusive (max,or) scan over PB positions ----
    if (tid < PB) {
        const int myv = tloc[8 + tid];
        int cs_scan = (myv == TOK_CS) ? (start + tid) : -1;
        int ce_scan = (myv == TOK_CE) ? 1 : 0;

        #pragma unroll
        for (int off = 1; off < PB; off <<= 1) {
            int u = __shfl_up(cs_scan, off);
            int w = __shfl_up(ce_scan, off);
            if (tid >= off) {
                if (u > cs_scan) cs_scan = u;
                ce_scan |= w;
            }
        }
        if (carry_cs > cs_scan) cs_scan = carry_cs;
        ce_scan |= carry_ce;

        const int i = start + tid;
        const int v = myv;
        unsigned long long m = ((unsigned long long)v) << 52;

        // code-region address one-hot
        if (cs_scan >= 0 && ce_scan == 0 && v < 256) {
            int sp = i - cs_scan - 1;
            if (sp >= 0) {
                int bo = sp & 7;
                if (bo < 5) {
                    int addr = ((sp >> 3) << 3) + 2 + bo;   // PC_OFFSET=2
                    addr &= 4095;
                    m |= (1ull << (addr & 15))
                       | (1ull << (16 + ((addr >> 4) & 15)))
                       | (1ull << (32 + ((addr >> 8) & 15)));
                }
            }
        }

        // MEM-op scatter, gathered from up to 8 positions back
        #pragma unroll
        for (int off = 0; off < 4; ++off) {
            int jj = i - 5 - off;
            int lj = jj - start + 8;            // >= 0 since jj >= i-8 >= start-8
            if (jj >= 0 && (jj + 8) < SS && tloc[lj] == TOK_MEM) {
                int a = ((tloc[lj + 1] | (tloc[lj + 2] << 8)) & 4095) + off;
                a &= 4095;
                m |= (1ull << (a & 15))
                   | (1ull << (16 + ((a >> 4) & 15)))
                   | (1ull << (32 + ((a >> 8) & 15)));
            }
        }

        // flag dims
        if (v == TOK_TS) m |= (1ull << 48);
        if (v == TOK_TE) m |= (1ull << 49);
        if (v == TOK_MEM && (i + 8) < SS) m |= (1ull << 50);

        mlds[tid] = m;
    }
    __syncthreads();

    // ---- phase C: writer. 2 positions / iter, 128 f4 lanes each ----
    const int k = tid & 127;
    const int half = tid >> 7;                  // 0 or 1
    vfloat4* orow = out + ((size_t)row * SS + start) * 128;

    #pragma unroll 8
    for (int it = 0; it < PB / 2; ++it) {
        const int pl = it * 2 + half;
        const unsigned long long m = mlds[pl];
        const int tok = (int)(m >> 52);

        vfloat4 v = embed4[tok * 128 + k];

        if (k >= 51 && k <= 63) {
            const int d0 = k * 4;
            #pragma unroll
            for (int j = 0; j < 4; ++j) {
                int r = d0 + j - 206;
                if (r >= 0 && r < 48 && ((m >> r) & 1ull)) v[j] = 1.0f;
            }
        } else if (k == 114) {
            #pragma unroll
            for (int j = 0; j < 3; ++j) {
                if ((m >> (48 + j)) & 1ull) v[j] = 1.0f;
            }
        }

        __builtin_nontemporal_store(v, &orow[pl * 128 + k]);
    }
}

extern "C" void kernel_launch(void* const* d_in, const int* in_sizes, int n_in,
                              void* d_out, int out_size, void* d_ws, size_t ws_size,
                              hipStream_t stream) {
    const float* embed = (const float*)d_in[0];   // [272, 512] fp32
    const int* tokens = (const int*)d_in[1];      // [8, 8192] int32

    fused_kernel<<<BB * SEGS, 256, 0, stream>>>(
        tokens, (const vfloat4*)embed, (vfloat4*)d_out);
}